// Round 1
// baseline (6111.704 us; speedup 1.0000x reference)
//
#include <hip/hip_runtime.h>
#include <stdint.h>

#define NB 256
#define NBATCH 128
#define HID 64
#define MAXEV 5
#define MAXSTEPS 256
#define NT 43          /* 43*6 = 258 >= 256 */
#define NTILES 946     /* 43*44/2 */
#define W2S 65         /* padded LDS stride for W2 rows */

struct EvRec { int code; int i; int jw; float dte; };      // code: 1 ball_a, 2 ball_b, 3 wall_a, 4 wall_b
struct StepLog { int n_ev; float final_dte; EvRec ev[MAXEV]; };

__device__ __forceinline__ float bf2f(unsigned short u) {
    return __uint_as_float(((unsigned)u) << 16);
}
__device__ __forceinline__ unsigned short f2bf(float f) {  // round-to-nearest-even
    unsigned u = __float_as_uint(f);
    u += 0x7FFFu + ((u >> 16) & 1u);
    return (unsigned short)(u >> 16);
}
__device__ __forceinline__ float rdin(const void* p, int idx, int bf) {
    return bf ? bf2f(((const unsigned short*)p)[idx]) : ((const float*)p)[idx];
}
__device__ __forceinline__ float silu_f(float x) {
    // x * sigmoid(x), sigmoid = 1/(1+exp(-x))
    float s = __fdiv_rn(1.0f, __fadd_rn(1.0f, expf(-x)));
    return __fmul_rn(x, s);
}
__device__ __forceinline__ unsigned long long shfl_down_u64(unsigned long long v, int off) {
    unsigned lo = (unsigned)v, hi = (unsigned)(v >> 32);
    lo = __shfl_down(lo, off);
    hi = __shfl_down(hi, off);
    return (((unsigned long long)hi) << 32) | lo;
}

__device__ void load_weights(float* w1, float* b1s, float* w2, float* b2s, float* w3, float* b3s,
                             const void* W1, const void* B1, const void* W2, const void* B2,
                             const void* W3, const void* B3, int bf, int tid, int nthr) {
    for (int k = tid; k < HID * 2; k += nthr) w1[k] = rdin(W1, k, bf);
    for (int k = tid; k < HID; k += nthr) {
        b1s[k] = rdin(B1, k, bf);
        b2s[k] = rdin(B2, k, bf);
        w3[k]  = rdin(W3, k, bf);
    }
    for (int k = tid; k < HID * HID; k += nthr) {
        int m = k >> 6, c = k & 63;
        w2[m * W2S + c] = rdin(W2, k, bf);
    }
    if (tid == 0) b3s[0] = rdin(B3, 0, bf);
}

// _apply_jump, exact reference op order. Uses sc[0..131] scratch. All threads enter.
__device__ void apply_ball(float* sx, float* sy, float* svx, float* svy,
                           const float* w1, const float* b1s, const float* w2, const float* b2s,
                           const float* w3, const float* b3s, float* sc, int i, int j, int tid) {
    if (tid == 0) {
        float dx = __fsub_rn(sx[j], sx[i]), dy = __fsub_rn(sy[j], sy[i]);
        float nrm = __fsqrt_rn(__fadd_rn(__fmul_rn(dx, dx), __fmul_rn(dy, dy)));
        float dist = fmaxf(nrm, 1e-8f);
        float nx = __fdiv_rn(dx, dist), ny = __fdiv_rn(dy, dist);
        float dvx = __fsub_rn(svx[j], svx[i]), dvy = __fsub_rn(svy[j], svy[i]);
        float app = __fadd_rn(__fmul_rn(dvx, nx), __fmul_rn(dvy, ny));
        sc[0] = nx; sc[1] = ny; sc[2] = dist; sc[3] = app;
    }
    __syncthreads();
    if (tid < HID) {
        float a = __fadd_rn(__fadd_rn(__fmul_rn(sc[2], w1[2 * tid]),
                                      __fmul_rn(sc[3], w1[2 * tid + 1])), b1s[tid]);
        sc[4 + tid] = silu_f(a);
    }
    __syncthreads();
    if (tid < HID) {
        float acc = 0.0f;
        const float* row = &w2[tid * W2S];
        #pragma unroll 8
        for (int k = 0; k < HID; k++) acc = __fadd_rn(acc, __fmul_rn(sc[4 + k], row[k]));
        acc = __fadd_rn(acc, b2s[tid]);
        sc[68 + tid] = silu_f(acc);
    }
    __syncthreads();
    if (tid == 0) {
        float acc = 0.0f;
        for (int k = 0; k < HID; k++) acc = __fadd_rn(acc, __fmul_rn(sc[68 + k], w3[k]));
        acc = __fadd_rn(acc, b3s[0]);
        float ix = __fmul_rn(acc, sc[0]), iy = __fmul_rn(acc, sc[1]);
        svx[i] = __fadd_rn(svx[i], ix);  svy[i] = __fadd_rn(svy[i], iy);
        svx[j] = __fadd_rn(svx[j], -ix); svy[j] = __fadd_rn(svy[j], -iy);
    }
    __syncthreads();
}

// _apply_wall, exact reference op order.
__device__ void apply_wall(float* sx, float* sy, float* svx, float* svy,
                           const float* rad, int i, int w, int tid) {
    if (tid == 0) {
        const float wnx[4] = {1.f, -1.f, 0.f, 0.f};
        const float wny[4] = {0.f, 0.f, 1.f, -1.f};
        const float wpv[4] = {0.f, -10.f, 0.f, -10.f};
        float vx = svx[i], vy = svy[i], px = sx[i], py = sy[i];
        float vn = __fadd_rn(__fmul_rn(vx, wnx[w]), __fmul_rn(vy, wny[w]));
        float t2 = __fmul_rn(2.0f, vn);
        svx[i] = __fsub_rn(vx, __fmul_rn(t2, wnx[w]));
        svy[i] = __fsub_rn(vy, __fmul_rn(t2, wny[w]));
        float pn = __fadd_rn(__fmul_rn(px, wnx[w]), __fmul_rn(py, wny[w]));
        float pen = fmaxf(__fsub_rn(__fadd_rn(wpv[w], rad[i]), pn), 0.0f);
        sx[i] = __fadd_rn(px, __fmul_rn(pen, wnx[w]));
        sy[i] = __fadd_rn(py, __fmul_rn(pen, wny[w]));
    }
    __syncthreads();
}

__device__ void integrate_all(float* sx, float* sy, const float* svx, const float* svy,
                              float dte, int tid) {
    if (tid < NB) {
        sx[tid] = __fadd_rn(sx[tid], __fmul_rn(svx[tid], dte));
        sy[tid] = __fadd_rn(sy[tid], __fmul_rn(svy[tid], dte));
    }
    __syncthreads();
}

__device__ void store_row(void* out, int bf, int s1, int b,
                          const float* sx, const float* sy, const float* svx, const float* svy,
                          int tid) {
    if (tid < NB) {
        long long base = ((long long)s1 * NBATCH + b) * (NB * 4);
        float x = sx[tid], y = sy[tid], vx = svx[tid], vy = svy[tid];
        if (bf) {
            ushort4 v;
            v.x = f2bf(x); v.y = f2bf(y); v.z = f2bf(vx); v.w = f2bf(vy);
            ((ushort4*)((unsigned short*)out + base))[tid] = v;
        } else {
            float4 v;
            v.x = x; v.y = y; v.z = vx; v.w = vy;
            ((float4*)((float*)out + base))[tid] = v;
        }
    }
}

// ---------------- dtype sniffer ----------------
// bf16 state values are bounded (~10). fp32 data read as ushorts exposes random
// exponents in the low halves -> values >= 64 certain among 256 samples.
__global__ void sniff_kernel(const unsigned short* st, int* ws) {
    __shared__ int ev;
    if (threadIdx.x == 0) ev = 0;
    __syncthreads();
    unsigned short u = st[threadIdx.x];
    int e = (u >> 7) & 0xFF;
    if (e >= 0x85) atomicOr(&ev, 1);
    __syncthreads();
    if (threadIdx.x == 0) ws[0] = ev ? 0 : 1;   // 1 = bf16, 0 = fp32
}

// ---------------- output row 0 = initial state (bit copy) ----------------
__global__ void row0_kernel(const void* in, void* out, const int* ws) {
    int idx = blockIdx.x * blockDim.x + threadIdx.x;
    if (ws[0]) ((unsigned short*)out)[idx] = ((const unsigned short*)in)[idx];
    else       ((float*)out)[idx] = ((const float*)in)[idx];
}

// ---------------- phase 1: batch-0 event simulation + event log ----------------
__global__ __launch_bounds__(1024, 1) void phase1_kernel(
    const void* in_state, const void* in_rad,
    const void* inW1, const void* inB1, const void* inW2, const void* inB2,
    const void* inW3, const void* inB3, const void* in_dt, const int* in_nsteps,
    void* out, int* ws) {
    __shared__ float sx[NB], sy[NB], svx[NB], svy[NB], rad[NB];
    __shared__ float w1[HID * 2], b1s[HID], w2[HID * W2S], b2s[HID], w3[HID], b3s[1];
    __shared__ float sc[160];
    __shared__ unsigned long long redP[16], redW[16];
    __shared__ int dI[4];
    __shared__ float dF[4];

    int tid = threadIdx.x;
    int bf = ws[0];
    StepLog* logp = (StepLog*)(ws + 16);

    if (tid < NB) {
        sx[tid]  = rdin(in_state, tid * 4 + 0, bf);
        sy[tid]  = rdin(in_state, tid * 4 + 1, bf);
        svx[tid] = rdin(in_state, tid * 4 + 2, bf);
        svy[tid] = rdin(in_state, tid * 4 + 3, bf);
        rad[tid] = rdin(in_rad, tid, bf);
    }
    load_weights(w1, b1s, w2, b2s, w3, b3s, inW1, inB1, inW2, inB2, inW3, inB3, bf, tid, 1024);
    __syncthreads();

    float dtv = rdin(in_dt, 0, bf);
    float rsum = __fadd_rn(rad[0], rad[0]);      // radii are uniform
    int NS = in_nsteps[0]; if (NS > MAXSTEPS) NS = MAXSTEPS; if (NS < 0) NS = 0;

    // tile assignment: upper-triangular (incl. diag) 43x43 tile grid of 6x6 ball blocks
    int bi = 0, bj = 0, hasT = 0;
    if (tid < NTILES) {
        int rem = tid, r = 0;
        while (rem >= NT - r) { rem -= NT - r; r++; }
        bi = r; bj = r + rem; hasT = 1;
    }
    int i0 = bi * 6, j0 = bj * 6;

    for (int s = 0; s < NS; s++) {
        float t_s = __fmul_rn((float)s, dtv);
        float t_e = __fadd_rn(t_s, dtv);
        float t_c = t_s;
        int n_ev = 0;

        for (int e = 0; e < MAXEV; e++) {
            unsigned long long kP = ~0ull, kW = ~0ull;
            if (hasT) {
                float xi[6], yi[6], ui[6], vi[6], xj[6], yj[6], uj[6], vj[6];
                #pragma unroll
                for (int a = 0; a < 6; a++) {
                    int ii = i0 + a; ii = ii < NB ? ii : NB - 1;
                    xi[a] = sx[ii]; yi[a] = sy[ii]; ui[a] = svx[ii]; vi[a] = svy[ii];
                    int jj = j0 + a; jj = jj < NB ? jj : NB - 1;
                    xj[a] = sx[jj]; yj[a] = sy[jj]; uj[a] = svx[jj]; vj[a] = svy[jj];
                }
                #pragma unroll
                for (int a = 0; a < 6; a++) {
                    int i = i0 + a;
                    #pragma unroll
                    for (int b = 0; b < 6; b++) {
                        int j = j0 + b;
                        bool ok = (i < NB) && (j < NB) && (j > i);
                        float dx = __fsub_rn(xj[b], xi[a]);
                        float dy = __fsub_rn(yj[b], yi[a]);
                        float d2 = __fadd_rn(__fmul_rn(dx, dx), __fmul_rn(dy, dy));
                        float p1 = __fmul_rn(__fsub_rn(uj[b], ui[a]), dx);
                        float p2 = __fmul_rn(__fsub_rn(vj[b], vi[a]), dy);
                        float dot = __fadd_rn(p1, p2);
                        float mag = __fadd_rn(fabsf(p1), fabsf(p2));
                        bool appr;
                        if (fabsf(dot) < __fmul_rn(1e-5f, mag)) {
                            // borderline: reproduce reference app_b exactly
                            float dist = __fsqrt_rn(d2);
                            float den = __fadd_rn(dist, 1e-8f);
                            float ab = __fadd_rn(
                                __fmul_rn(__fsub_rn(uj[b], ui[a]), __fdiv_rn(dx, den)),
                                __fmul_rn(__fsub_rn(vj[b], vi[a]), __fdiv_rn(dy, den)));
                            appr = ab < 0.0f;
                        } else {
                            appr = dot < 0.0f;
                        }
                        if (ok && appr) {
                            unsigned long long key =
                                (((unsigned long long)__float_as_uint(d2)) << 16) |
                                (unsigned)((i << 8) | j);
                            kP = key < kP ? key : kP;
                        }
                    }
                }
            }
            {   // wall candidate: one per thread, id = ball*4+w = tid
                int ball = tid >> 2, w = tid & 3;
                float px = sx[ball], py = sy[ball], vx = svx[ball], vy = svy[ball], r = rad[ball];
                float g; bool valid;
                if (w == 0)      { g = __fsub_rn(px, r); valid = vx < 0.0f; }
                else if (w == 1) { g = __fsub_rn(__fsub_rn(10.0f, px), r); valid = vx > 0.0f; }
                else if (w == 2) { g = __fsub_rn(py, r); valid = vy < 0.0f; }
                else             { g = __fsub_rn(__fsub_rn(10.0f, py), r); valid = vy > 0.0f; }
                if (valid) {
                    unsigned gb = __float_as_uint(g);
                    unsigned m = (unsigned)(((int)gb) >> 31) | 0x80000000u;
                    unsigned sb = gb ^ m;  // order-preserving map incl. negatives
                    kW = (((unsigned long long)sb) << 16) | (unsigned)tid;
                }
            }
            // reduction: wave-level then block-level, tie -> lowest index
            #pragma unroll
            for (int off = 32; off; off >>= 1) {
                unsigned long long o1 = shfl_down_u64(kP, off);
                unsigned long long o2 = shfl_down_u64(kW, off);
                kP = o1 < kP ? o1 : kP;
                kW = o2 < kW ? o2 : kW;
            }
            if ((tid & 63) == 0) { redP[tid >> 6] = kP; redW[tid >> 6] = kW; }
            __syncthreads();
            if (tid == 0) {
                unsigned long long mP = redP[0], mW = redW[0];
                for (int q = 1; q < 16; q++) {
                    mP = redP[q] < mP ? redP[q] : mP;
                    mW = redW[q] < mW ? redW[q] : mW;
                }
                float gball = 1e30f; int pi = 0, pj = 1;
                if (mP != ~0ull) {
                    unsigned id = (unsigned)(mP & 0xFFFFull);
                    pi = id >> 8; pj = id & 255u;
                    float d2 = __uint_as_float((unsigned)(mP >> 16));
                    gball = __fsub_rn(__fsqrt_rn(d2), rsum);
                }
                float gwall = 1e30f; int wb = 0, ww = 0;
                if (mW != ~0ull) {
                    unsigned id = (unsigned)(mW & 0xFFFFull);
                    wb = id >> 2; ww = id & 3u;
                    unsigned sb = (unsigned)(mW >> 16);
                    unsigned gb = (sb & 0x80000000u) ? (sb ^ 0x80000000u) : ~sb;
                    gwall = __uint_as_float(gb);
                }
                bool is_ball = gball <= gwall;   // pairs precede walls in argmin order
                float gap = is_ball ? gball : gwall;
                int code = 0; float dte = 0.0f, tcn = t_c;
                if (!(gap > 0.05f)) {
                    float app;
                    if (is_ball) {
                        float dx = __fsub_rn(sx[pj], sx[pi]), dy = __fsub_rn(sy[pj], sy[pi]);
                        float nrm = __fsqrt_rn(__fadd_rn(__fmul_rn(dx, dx), __fmul_rn(dy, dy)));
                        float dvx = __fsub_rn(svx[pj], svx[pi]), dvy = __fsub_rn(svy[pj], svy[pi]);
                        app = -__fadd_rn(__fdiv_rn(__fmul_rn(dvx, dx), nrm),
                                         __fdiv_rn(__fmul_rn(dvy, dy), nrm));
                    } else {
                        app = fabsf(fmaxf(svx[wb], svy[wb]));
                    }
                    float t_ev = __fadd_rn(t_c, __fdiv_rn(gap, fmaxf(app, 1e-6f)));
                    if (gap <= 0.0f) {
                        code = is_ball ? 1 : 3;
                    } else if (app > 1e-6f && t_ev < t_e) {
                        code = is_ball ? 2 : 4;
                        dte = (t_ev > __fadd_rn(t_c, 1e-10f)) ? __fsub_rn(t_ev, t_c) : 0.0f;
                        tcn = t_ev;
                    }
                }
                dI[0] = code;
                dI[1] = is_ball ? pi : wb;
                dI[2] = is_ball ? pj : ww;
                dF[0] = dte; dF[1] = tcn;
                if (code != 0) {
                    EvRec er; er.code = code; er.i = dI[1]; er.jw = dI[2]; er.dte = dte;
                    logp[s].ev[n_ev] = er;
                    n_ev++;
                }
            }
            __syncthreads();
            int code = dI[0];
            if (code == 0) break;
            int ei = dI[1], ejw = dI[2];
            float dte = dF[0];
            if (code == 2 || code == 4) integrate_all(sx, sy, svx, svy, dte, tid);
            if (code <= 2) apply_ball(sx, sy, svx, svy, w1, b1s, w2, b2s, w3, b3s, sc, ei, ejw, tid);
            else           apply_wall(sx, sy, svx, svy, rad, ei, ejw, tid);
            t_c = dF[1];
        }

        if (tid == 0) {
            float fd = (t_e > __fadd_rn(t_c, 1e-10f)) ? __fsub_rn(t_e, t_c) : 0.0f;
            dF[2] = fd;
            logp[s].final_dte = fd;
            logp[s].n_ev = n_ev;
        }
        __syncthreads();
        integrate_all(sx, sy, svx, svy, dF[2], tid);
        store_row(out, bf, s + 1, 0, sx, sy, svx, svy, tid);
        __syncthreads();
    }
}

// ---------------- phase 2: per-batch replay of the event log ----------------
__global__ __launch_bounds__(256, 1) void phase2_kernel(
    const void* in_state, const void* in_rad,
    const void* inW1, const void* inB1, const void* inW2, const void* inB2,
    const void* inW3, const void* inB3, const int* in_nsteps,
    void* out, int* ws) {
    __shared__ float sx[NB], sy[NB], svx[NB], svy[NB], rad[NB];
    __shared__ float w1[HID * 2], b1s[HID], w2[HID * W2S], b2s[HID], w3[HID], b3s[1];
    __shared__ float sc[160];

    int tid = threadIdx.x;
    int b = blockIdx.x + 1;                 // batch 0 handled by phase 1
    int bf = ws[0];
    const StepLog* logp = (const StepLog*)(ws + 16);

    if (tid < NB) {
        int base = b * NB * 4 + tid * 4;
        sx[tid]  = rdin(in_state, base + 0, bf);
        sy[tid]  = rdin(in_state, base + 1, bf);
        svx[tid] = rdin(in_state, base + 2, bf);
        svy[tid] = rdin(in_state, base + 3, bf);
        rad[tid] = rdin(in_rad, tid, bf);
    }
    load_weights(w1, b1s, w2, b2s, w3, b3s, inW1, inB1, inW2, inB2, inW3, inB3, bf, tid, 256);
    __syncthreads();

    int NS = in_nsteps[0]; if (NS > MAXSTEPS) NS = MAXSTEPS; if (NS < 0) NS = 0;

    for (int s = 0; s < NS; s++) {
        int ne = logp[s].n_ev;
        for (int e = 0; e < ne; e++) {
            EvRec er = logp[s].ev[e];
            if (er.code == 2 || er.code == 4) integrate_all(sx, sy, svx, svy, er.dte, tid);
            if (er.code <= 2) apply_ball(sx, sy, svx, svy, w1, b1s, w2, b2s, w3, b3s, sc, er.i, er.jw, tid);
            else              apply_wall(sx, sy, svx, svy, rad, er.i, er.jw, tid);
        }
        integrate_all(sx, sy, svx, svy, logp[s].final_dte, tid);
        store_row(out, bf, s + 1, b, sx, sy, svx, svy, tid);
        __syncthreads();
    }
}

extern "C" void kernel_launch(void* const* d_in, const int* in_sizes, int n_in,
                              void* d_out, int out_size, void* d_ws, size_t ws_size,
                              hipStream_t stream) {
    // inputs: 0 state, 1 radii, 2 W1, 3 b1, 4 W2, 5 b2, 6 W3, 7 b3, 8 dt, 9 n_steps
    int* ws = (int*)d_ws;
    sniff_kernel<<<1, 256, 0, stream>>>((const unsigned short*)d_in[0], ws);
    row0_kernel<<<(NBATCH * NB * 4) / 256, 256, 0, stream>>>(d_in[0], d_out, ws);
    phase1_kernel<<<1, 1024, 0, stream>>>(
        d_in[0], d_in[1], d_in[2], d_in[3], d_in[4], d_in[5], d_in[6], d_in[7],
        d_in[8], (const int*)d_in[9], d_out, ws);
    phase2_kernel<<<NBATCH - 1, 256, 0, stream>>>(
        d_in[0], d_in[1], d_in[2], d_in[3], d_in[4], d_in[5], d_in[6], d_in[7],
        (const int*)d_in[9], d_out, ws);
}